// Round 7
// baseline (20.924 us; speedup 1.0000x reference)
//
#include <hip/hip_runtime.h>

#define NN 64
#define KK 64
#define BETA_C 0.9f

// Single fused kernel. Block = (b, i, m-quarter). 512 threads = 8 waves.
// Phase A: stage W + mask slice; ALL 8 waves compute g1[b,i,:,:] -> LDS (8 rows each);
//          batch-0 walk loads + `old` prefetched BEFORE the GEMM (latency hides).
// Phase B: wave w walks m0 = q*16+2w, m1 = m0+1. Full-wave per-m accesses:
//          scalar j => saddr global loads (0 VALU addr) and conflict-free ds_read_b32.
//          Scalar ping-pong double-buffer, batches of 8 j's per m.
__global__ __launch_bounds__(512, 4) void walk_fused3(const float* __restrict__ graph,
                                                      const float* __restrict__ W,
                                                      const int* __restrict__ mask,
                                                      float* __restrict__ out) {
    __shared__ float Ws[KK][KK];    // 16 KB, Ws[k][l]
    __shared__ float g1s[NN][KK];   // 16 KB
    __shared__ int   ms[NN][17];    // 4.25 KB, pad 17 (coprime 32) -> <=2-way (free)

    int bid = blockIdx.x;
    // decode: q = m-quarter (low bits: XCD-spread), then b, then i.
    int q  = bid & 3;
    int Bc = gridDim.x >> 8;                 // grid = B*NN*4; >>2 then /NN
    int r  = bid >> 2;
    int b  = (Bc == 2) ? (r & 1) : (r % Bc);
    int i  = (Bc == 2) ? (r >> 1) : (r / Bc);

    int t    = threadIdx.x;
    int lane = t & 63;                                   // k (doubles as j for ballot)
    int w    = __builtin_amdgcn_readfirstlane(t >> 6);   // wave id 0..7, SGPR

    size_t biBase = (size_t)(b * NN + i);

    // ---- stage W (two float4 per thread) ----
    {
        float4* wd = (float4*)&Ws[0][0];
        const float4* wsrc = (const float4*)W;
        wd[t]       = wsrc[t];
        wd[t + 512] = wsrc[t + 512];
    }
    // ---- stage mask[b,i,:,q*16 .. q*16+15] (2 ints per thread, 64B rows) ----
    {
        const int* mbase = mask + (biBase * NN) * NN + q * 16;
        int j0 = t >> 4, c0 = t & 15;
        ms[j0][c0]      = mbase[(size_t)j0 * NN + c0];
        ms[j0 + 32][c0] = mbase[(size_t)(j0 + 32) * NN + c0];
    }
    __syncthreads();

    // ---- walk setup: validity bitmasks (lane plays j) ----
    int m0 = q * 16 + 2 * w;
    int m1 = m0 + 1;
    bool v0 = (ms[lane][2 * w + 0] != 0) & (lane != m0) & (lane != i);
    bool v1 = (ms[lane][2 * w + 1] != 0) & (lane != m1) & (lane != i);
    unsigned long long vm0 = __ballot(v0);               // SGPR pair
    unsigned long long vm1 = __ballot(v1);
    if (i == m0) vm0 = 0ULL;
    if (i == m1) vm1 = 0ULL;

    const float* gm0 = graph + ((size_t)b * NN * NN + m0) * KK;  // + j*NN*KK + lane
    const float* gm1 = graph + ((size_t)b * NN * NN + m1) * KK;

    int  jA0[8], jA1[8], jB0[8], jB1[8];
    bool lA0[8], lA1[8], lB0[8], lB1[8];
    float gvA0[8], gvA1[8], gvB0[8], gvB1[8];

    // scalar extract + issue saddr loads (8 j's per m)
    auto extract = [&](int* j0a, int* j1a, bool* l0a, bool* l1a,
                       float* gv0, float* gv1) {
#pragma unroll
        for (int n = 0; n < 8; ++n) {
            l0a[n] = (vm0 != 0ULL);
            j0a[n] = (int)__builtin_ctzll(l0a[n] ? vm0 : 1ULL);  // scalar, 0 when dead
            vm0 &= vm0 - 1ULL;
            l1a[n] = (vm1 != 0ULL);
            j1a[n] = (int)__builtin_ctzll(l1a[n] ? vm1 : 1ULL);
            vm1 &= vm1 - 1ULL;
            gv0[n] = gm0[(size_t)j0a[n] * (NN * KK) + lane];     // SGPR base -> saddr
            gv1[n] = gm1[(size_t)j1a[n] * (NN * KK) + lane];
        }
    };

    float ac0 = 0.f, ab0 = 0.f, ac1 = 0.f, ab1 = 0.f;
    auto consume = [&](int* j0a, int* j1a, bool* l0a, bool* l1a,
                       float* gv0, float* gv1) {
#pragma unroll
        for (int n = 0; n < 8; ++n) {
            float w0v = g1s[j0a[n]][lane];   // full-wave row read: conflict-free
            float w1v = g1s[j1a[n]][lane];
            float p0 = l0a[n] ? gv0[n] * w0v : 0.f;
            float p1 = l1a[n] ? gv1[n] * w1v : 0.f;
            ac0 += p0; ab0 += fabsf(p0);     // |.| folds to input modifier
            ac1 += p1; ab1 += fabsf(p1);
        }
    };

    // ---- peel: issue batch-0 loads + `old` BEFORE the GEMM ----
    bool haveA = ((vm0 | vm1) != 0ULL);
    if (haveA) extract(jA0, jA1, lA0, lA1, gvA0, gvA1);
    float old0 = gm0[(size_t)i * (NN * KK) + lane];   // graph[b,i,m0,lane]
    float old1 = gm1[(size_t)i * (NN * KK) + lane];

    // ---- Phase A: GEMM g1s = graph[b,i,:,:] @ W, 8 rows per wave ----
    {
        int r0 = w * 8;
        const float4* a = (const float4*)(graph + (biBase * NN + r0) * KK); // 16 f4/row
        float acc[8] = {0.f, 0.f, 0.f, 0.f, 0.f, 0.f, 0.f, 0.f};
#pragma unroll
        for (int k4 = 0; k4 < 16; ++k4) {
            float4 x[8];
#pragma unroll
            for (int rr = 0; rr < 8; ++rr) x[rr] = a[k4 + 16 * rr];  // broadcast loads
            float w0 = Ws[4 * k4 + 0][lane];
            float w1 = Ws[4 * k4 + 1][lane];
            float w2 = Ws[4 * k4 + 2][lane];
            float w3 = Ws[4 * k4 + 3][lane];
#pragma unroll
            for (int rr = 0; rr < 8; ++rr) {
                acc[rr] = fmaf(x[rr].x, w0, acc[rr]);
                acc[rr] = fmaf(x[rr].y, w1, acc[rr]);
                acc[rr] = fmaf(x[rr].z, w2, acc[rr]);
                acc[rr] = fmaf(x[rr].w, w3, acc[rr]);
            }
        }
#pragma unroll
        for (int rr = 0; rr < 8; ++rr) g1s[r0 + rr][lane] = acc[rr];
    }
    __syncthreads();

    // ---- Phase B: ping-pong double-buffered walk (no register copies) ----
    while (haveA) {
        bool haveB = ((vm0 | vm1) != 0ULL);
        if (haveB) extract(jB0, jB1, lB0, lB1, gvB0, gvB1);
        consume(jA0, jA1, lA0, lA1, gvA0, gvA1);
        if (!haveB) break;
        haveA = ((vm0 | vm1) != 0ULL);
        if (haveA) extract(jA0, jA1, lA0, lA1, gvA0, gvA1);
        consume(jB0, jB1, lB0, lB1, gvB0, gvB1);
    }

    // ---- epilogue: lerp with beta ----
    {
        size_t o0 = (biBase * NN + m0) * KK + lane;
        size_t o1 = (biBase * NN + m1) * KK + lane;
        float nw0 = (ac0 + ab0) * 0.5f;               // == sum(relu(p)) exactly
        float nw1 = (ac1 + ab1) * 0.5f;
        float be0 = (ab0 != 0.f) ? BETA_C : 1.0f;     // anynz <=> sum|p| != 0
        float be1 = (ab1 != 0.f) ? BETA_C : 1.0f;
        out[o0] = nw0 + be0 * (old0 - nw0);
        out[o1] = nw1 + be1 * (old1 - nw1);
    }
}

extern "C" void kernel_launch(void* const* d_in, const int* in_sizes, int n_in,
                              void* d_out, int out_size, void* d_ws, size_t ws_size,
                              hipStream_t stream) {
    const float* graph = (const float*)d_in[0];
    const float* W     = (const float*)d_in[1];
    const int*   mask  = (const int*)d_in[2];
    float*       out   = (float*)d_out;

    int B = in_sizes[0] / (NN * NN * KK);     // 2
    walk_fused3<<<B * NN * 4, 512, 0, stream>>>(graph, W, mask, out);
}

// Round 8
// 19.754 us; speedup vs baseline: 1.0593x; 1.0593x over previous
//
#include <hip/hip_runtime.h>

#define NN 64
#define KK 64
#define BETA_C 0.9f

// Single fused kernel. Block = (b, i, m-half). 1024 threads = 16 waves.
// Phase A: stage W + mask slice; waves 0..7 compute g1[b,i,:,:] -> LDS (8 rows each);
//          every wave pre-issues its batch-0 walk loads + `old` BEFORE the GEMM.
// Phase B: wave w handles m0 = mh*32+2w (lanes 0..31) and m1 = m0+1 (lanes 32..63);
//          each lane owns a k-pair (float2). SEPARATE scalar j-lists per m
//          (SGPR extraction, trip = max(|vm0|,|vm1|) ~ 33), one ds_read_b64 +
//          one global_load_dwordx2 per j-step, batch-8 ping-pong double buffer.
__global__ __launch_bounds__(1024, 4) void walk_fused4(const float* __restrict__ graph,
                                                       const float* __restrict__ W,
                                                       const int* __restrict__ mask,
                                                       float* __restrict__ out) {
    __shared__ float Ws[KK][KK];    // 16 KB, Ws[k][l]
    __shared__ float g1s[NN][KK];   // 16 KB
    __shared__ int   ms[NN][33];    // 8.25 KB, pad 33 -> <=2-way (free)

    int bid = blockIdx.x;
    int b, i, mh;
    if (gridDim.x == 256) {
        // XCD-clustered decode: same bid%8 -> same XCD; blocks on one XCD share
        // the gcol working set graph[b,:,mh*32..,:] (~2 MB, fits a 4 MB XCD L2).
        int xcdsel = bid & 7;
        b  = xcdsel >> 2;
        mh = (xcdsel >> 1) & 1;
        i  = ((xcdsel & 1) << 5) | (bid >> 3);
    } else {
        mh = bid & 1;
        i  = (bid >> 1) & 63;
        b  = bid >> 7;
    }

    int t    = threadIdx.x;
    int lane = t & 63;                                   // ballot: j ; walk: half|kp
    int w    = __builtin_amdgcn_readfirstlane(t >> 6);   // wave id 0..15, SGPR

    size_t biBase = (size_t)(b * NN + i);

    // ---- stage W (one float4 per thread) ----
    ((float4*)&Ws[0][0])[t] = ((const float4*)W)[t];

    // ---- stage mask[b,i,:,mh*32 .. mh*32+31] (2 ints per thread) ----
    {
        const int* mbase = mask + (biBase * NN) * NN + mh * 32;
        int j = t >> 5, c = t & 31;
        ms[j][c]      = mbase[(size_t)j * NN + c];
        ms[j + 32][c] = mbase[(size_t)(j + 32) * NN + c];
    }
    __syncthreads();

    // ---- walk setup: validity bitmasks (lane plays j) ----
    int m0 = mh * 32 + 2 * w;
    int m1 = m0 + 1;
    bool v0 = (ms[lane][2 * w + 0] != 0) & (lane != m0) & (lane != i);
    bool v1 = (ms[lane][2 * w + 1] != 0) & (lane != m1) & (lane != i);
    unsigned long long vm0 = __ballot(v0);               // SGPR pair
    unsigned long long vm1 = __ballot(v1);
    if (i == m0) vm0 = 0ULL;
    if (i == m1) vm1 = 0ULL;

    int half = lane >> 5;                  // 0 -> m0, 1 -> m1
    int kp   = lane & 31;                  // owns k = {2kp, 2kp+1}

    // per-lane constant parts of the walk addresses (element units)
    const float* gslab = graph + (size_t)b * NN * NN * KK + (size_t)m0 * KK
                       + (size_t)half * KK + 2 * kp;     // + j*NN*KK walks rows
    const float* g1f   = &g1s[0][0];
    int lconst = half ? 1 : 0;                           // select helper

    int   jS0[8], jS1[8], jT0[8], jT1[8];
    bool  lS0[8], lS1[8], lT0[8], lT1[8];
    float2 gvS[8], gvT[8];

    // scalar extract + issue one dwordx2 per j-step (covers both halves)
    auto extract = [&](int* j0a, int* j1a, bool* l0a, bool* l1a, float2* gv) {
#pragma unroll
        for (int n = 0; n < 8; ++n) {
            l0a[n] = (vm0 != 0ULL);
            j0a[n] = (int)__builtin_ctzll(l0a[n] ? vm0 : 1ULL);   // scalar
            vm0 &= vm0 - 1ULL;
            l1a[n] = (vm1 != 0ULL);
            j1a[n] = (int)__builtin_ctzll(l1a[n] ? vm1 : 1ULL);
            vm1 &= vm1 - 1ULL;
            int jsel = lconst ? j1a[n] : j0a[n];                  // 1 cndmask
            gv[n] = *(const float2*)(gslab + (size_t)jsel * (NN * KK));
        }
    };

    float ax = 0.f, sx = 0.f, ay = 0.f, sy = 0.f;
    auto consume = [&](int* j0a, int* j1a, bool* l0a, bool* l1a, float2* gv) {
#pragma unroll
        for (int n = 0; n < 8; ++n) {
            int jsel = lconst ? j1a[n] : j0a[n];
            float2 gw = *(const float2*)(g1f + jsel * KK + 2 * kp); // ds_read_b64
            bool vld  = lconst ? l1a[n] : l0a[n];
            float px = vld ? gv[n].x * gw.x : 0.f;
            float py = vld ? gv[n].y * gw.y : 0.f;
            ax += px; sx += fabsf(px);    // |.| folds to VOP3 input modifier
            ay += py; sy += fabsf(py);
        }
    };

    // ---- peel: issue batch-0 loads + `old` BEFORE the GEMM ----
    bool haveS = ((vm0 | vm1) != 0ULL);
    if (haveS) extract(jS0, jS1, lS0, lS1, gvS);
    float2 old2 = *(const float2*)(gslab + (size_t)i * (NN * KK)); // graph[b,i,m,kpair]

    // ---- Phase A: GEMM g1s = graph[b,i,:,:] @ W, waves 0..7, 8 rows each ----
    if (w < 8) {
        int r0 = w * 8;
        const float4* a = (const float4*)(graph + (biBase * NN + r0) * KK); // 16 f4/row
        float acc[8] = {0.f, 0.f, 0.f, 0.f, 0.f, 0.f, 0.f, 0.f};
#pragma unroll
        for (int k4 = 0; k4 < 16; ++k4) {
            float4 x[8];
#pragma unroll
            for (int r = 0; r < 8; ++r) x[r] = a[k4 + 16 * r];   // uniform -> s_load
            float w0 = Ws[4 * k4 + 0][lane];
            float w1 = Ws[4 * k4 + 1][lane];
            float w2 = Ws[4 * k4 + 2][lane];
            float w3 = Ws[4 * k4 + 3][lane];
#pragma unroll
            for (int r = 0; r < 8; ++r) {
                acc[r] = fmaf(x[r].x, w0, acc[r]);
                acc[r] = fmaf(x[r].y, w1, acc[r]);
                acc[r] = fmaf(x[r].z, w2, acc[r]);
                acc[r] = fmaf(x[r].w, w3, acc[r]);
            }
        }
#pragma unroll
        for (int r = 0; r < 8; ++r) g1s[r0 + r][lane] = acc[r];
    }
    __syncthreads();

    // ---- Phase B: ping-pong double-buffered walk ----
    while (haveS) {
        bool haveT = ((vm0 | vm1) != 0ULL);
        if (haveT) extract(jT0, jT1, lT0, lT1, gvT);
        consume(jS0, jS1, lS0, lS1, gvS);
        if (!haveT) break;
        haveS = ((vm0 | vm1) != 0ULL);
        if (haveS) extract(jS0, jS1, lS0, lS1, gvS);
        consume(jT0, jT1, lT0, lT1, gvT);
    }

    // ---- epilogue: lerp with beta (per component), one dwordx2 store ----
    {
        size_t o2 = (biBase * NN + m0) * KK + (size_t)half * KK + 2 * kp;
        float nwx = (ax + sx) * 0.5f;                 // == sum(relu(p)) exactly
        float nwy = (ay + sy) * 0.5f;
        float bx = (sx != 0.f) ? BETA_C : 1.0f;       // anynz <=> sum|p| != 0
        float by = (sy != 0.f) ? BETA_C : 1.0f;
        float2 res;
        res.x = nwx + bx * (old2.x - nwx);
        res.y = nwy + by * (old2.y - nwy);
        *(float2*)(out + o2) = res;
    }
}

extern "C" void kernel_launch(void* const* d_in, const int* in_sizes, int n_in,
                              void* d_out, int out_size, void* d_ws, size_t ws_size,
                              hipStream_t stream) {
    const float* graph = (const float*)d_in[0];
    const float* W     = (const float*)d_in[1];
    const int*   mask  = (const int*)d_in[2];
    float*       out   = (float*)d_out;

    int B = in_sizes[0] / (NN * NN * KK);     // 2
    walk_fused4<<<B * NN * 2, 1024, 0, stream>>>(graph, W, mask, out);
}

// Round 9
// 19.051 us; speedup vs baseline: 1.0983x; 1.0369x over previous
//
#include <hip/hip_runtime.h>

#define NN 64
#define KK 64
#define BETA_C 0.9f

// Single fused kernel (best-measured variant, R5 = 18.97 us).
// Block = (b, i, m-half). 1024 threads = 16 waves.
// Phase A: stage W + mask slice; waves 0..7 compute g1[b,i,:,:] -> LDS (8 rows/wave).
// Phase B: wave w walks m0 = mh*32 + 2w and m1 = m0+1 over the union validity mask,
//          scalar SALU batch extraction, saddr global loads, shared g1s ds_read.
__global__ __launch_bounds__(1024, 4) void walk_fused1(const float* __restrict__ graph,
                                                       const float* __restrict__ W,
                                                       const int* __restrict__ mask,
                                                       float* __restrict__ out) {
    __shared__ float Ws[KK][KK];    // 16 KB, Ws[k][l]
    __shared__ float g1s[NN][KK];   // 16 KB
    __shared__ int   ms[NN][33];    // 8.25 KB, pad 33 -> <=2-way (free)

    int bid = blockIdx.x;
    int b, i, mh;
    if (gridDim.x == 256) {
        // XCD-clustered decode: blocks with same (b, mh, i-half) share bid%8 -> same XCD;
        // their gcol working set graph[b, :, mh-half, :] fits one XCD L2.
        int xcdsel = bid & 7;
        b  = xcdsel >> 2;
        mh = (xcdsel >> 1) & 1;
        i  = ((xcdsel & 1) << 5) | (bid >> 3);
    } else {
        mh = bid & 1;
        i  = (bid >> 1) & 63;
        b  = bid >> 7;
    }

    int t    = threadIdx.x;
    int lane = t & 63;                                   // k (doubles as j for ballot)
    int w    = __builtin_amdgcn_readfirstlane(t >> 6);   // wave id 0..15, provably SGPR

    size_t biBase = (size_t)(b * NN + i);

    // ---- stage W (one float4 per thread) ----
    ((float4*)&Ws[0][0])[t] = ((const float4*)W)[t];

    // ---- stage mask[b,i,:,mh*32 .. mh*32+31] (2 ints per thread) ----
    {
        const int* mbase = mask + (biBase * NN) * NN + mh * 32;
        int j = t >> 5, c = t & 31;
        ms[j][c]      = mbase[(size_t)j * NN + c];
        ms[j + 32][c] = mbase[(size_t)(j + 32) * NN + c];
    }
    __syncthreads();

    // ---- Phase A: GEMM g1s = graph[b,i,:,:] @ W, waves 0..7, 8 rows each ----
    if (w < 8) {
        int r0 = w * 8;
        const float4* a = (const float4*)(graph + (biBase * NN + r0) * KK); // 16 f4/row
        float acc[8] = {0.f, 0.f, 0.f, 0.f, 0.f, 0.f, 0.f, 0.f};
#pragma unroll
        for (int k4 = 0; k4 < 16; ++k4) {
            float4 x[8];
#pragma unroll
            for (int r = 0; r < 8; ++r) x[r] = a[k4 + 16 * r];   // broadcast loads
            float w0 = Ws[4 * k4 + 0][lane];
            float w1 = Ws[4 * k4 + 1][lane];
            float w2 = Ws[4 * k4 + 2][lane];
            float w3 = Ws[4 * k4 + 3][lane];
#pragma unroll
            for (int r = 0; r < 8; ++r) {
                acc[r] = fmaf(x[r].x, w0, acc[r]);
                acc[r] = fmaf(x[r].y, w1, acc[r]);
                acc[r] = fmaf(x[r].z, w2, acc[r]);
                acc[r] = fmaf(x[r].w, w3, acc[r]);
            }
        }
#pragma unroll
        for (int r = 0; r < 8; ++r) g1s[r0 + r][lane] = acc[r];
    }
    __syncthreads();

    // ---- Phase B: walk two m's per wave over the union bitmask ----
    int m0 = mh * 32 + 2 * w;
    int m1 = m0 + 1;

    bool v0 = (ms[lane][2 * w + 0] != 0) & (lane != m0) & (lane != i);
    bool v1 = (ms[lane][2 * w + 1] != 0) & (lane != m1) & (lane != i);
    unsigned long long vm0 = __ballot(v0);
    unsigned long long vm1 = __ballot(v1);
    if (i == m0) vm0 = 0ULL;
    if (i == m1) vm1 = 0ULL;
    unsigned long long vmU = vm0 | vm1;

    const float* gb0 = graph + ((size_t)b * NN * NN + m0) * KK;  // SGPR bases -> saddr
    const float* gb1 = graph + ((size_t)b * NN * NN + m1) * KK;

    float a0 = 0.f, s0 = 0.f, a1 = 0.f, s1 = 0.f;
    while (vmU) {
        unsigned long long tv = vmU;
        int  jj[8];
        bool lv[8];
#pragma unroll
        for (int n = 0; n < 8; ++n) {
            lv[n] = (tv != 0ULL);
            jj[n] = (int)__builtin_ctzll(lv[n] ? tv : 1ULL);   // scalar, 0 when dead
            tv &= tv - 1ULL;
        }
        vmU = tv;
        float gv0[8], gv1[8], gw[8];
#pragma unroll
        for (int n = 0; n < 8; ++n) {
            gv0[n] = gb0[(size_t)jj[n] * (NN * KK) + lane];
            gv1[n] = gb1[(size_t)jj[n] * (NN * KK) + lane];
            gw[n]  = g1s[jj[n]][lane];                          // shared by both m's
        }
#pragma unroll
        for (int n = 0; n < 8; ++n) {
            bool c0 = lv[n] && (((vm0 >> jj[n]) & 1ULL) != 0ULL);
            bool c1 = lv[n] && (((vm1 >> jj[n]) & 1ULL) != 0ULL);
            float p0 = c0 ? gv0[n] * gw[n] : 0.f;
            float p1 = c1 ? gv1[n] * gw[n] : 0.f;
            a0 += p0; s0 += fabsf(p0);
            a1 += p1; s1 += fabsf(p1);
        }
    }

    // ---- epilogue: lerp with beta ----
    {
        size_t o0 = (biBase * NN + m0) * KK + lane;
        size_t o1 = (biBase * NN + m1) * KK + lane;
        float old0 = graph[o0];
        float old1 = graph[o1];
        float nw0 = (a0 + s0) * 0.5f;                 // == sum(relu(p)) exactly
        float nw1 = (a1 + s1) * 0.5f;
        float be0 = (s0 != 0.f) ? BETA_C : 1.0f;      // anynz <=> sum|p| != 0
        float be1 = (s1 != 0.f) ? BETA_C : 1.0f;
        out[o0] = nw0 + be0 * (old0 - nw0);
        out[o1] = nw1 + be1 * (old1 - nw1);
    }
}

extern "C" void kernel_launch(void* const* d_in, const int* in_sizes, int n_in,
                              void* d_out, int out_size, void* d_ws, size_t ws_size,
                              hipStream_t stream) {
    const float* graph = (const float*)d_in[0];
    const float* W     = (const float*)d_in[1];
    const int*   mask  = (const int*)d_in[2];
    float*       out   = (float*)d_out;

    int B = in_sizes[0] / (NN * NN * KK);     // 2
    walk_fused1<<<B * NN * 2, 1024, 0, stream>>>(graph, W, mask, out);
}